// Round 5
// baseline (26746.545 us; speedup 1.0000x reference)
//
#include <hip/hip_runtime.h>
#include <hip/hip_bf16.h>

#define N_   64
#define T_   1024
#define IN_  64
#define H1_  512
#define H2_  256
#define K1_  576    // IN_ + H1_
#define K2_  768    // H1_ + H2_
#define NBLK 24     // 16 layer-1 blocks + 8 layer-2 blocks
#define NB1  16
#define NB2  8

typedef __bf16 bf16x8 __attribute__((ext_vector_type(8)));
typedef float  f32x4  __attribute__((ext_vector_type(4)));
typedef unsigned int u32x4 __attribute__((ext_vector_type(4)));
typedef unsigned short u16x8 __attribute__((ext_vector_type(8)));
typedef unsigned long long u64;
typedef __hip_bfloat16 bf16_t;

// ---------------- workspace layout (bytes) ----------------
#define OFF_H1B   0u            // 4-deep ring: 4 * 64*512*2 = 262144
#define OFF_H2B   262144u       // 2-deep:      2 * 64*256*2 = 65536
#define OFF_BAR   327680u       // flag area: 24 flags x 128 B = 3072
#define ZERO_BYTES 330752u
#define OFF_XB    330752u       // 64*1024*64*2 = 8388608
#define OFF_W1    8719360u      // 2048*576*2 = 2359296
#define OFF_W2    11078656u     // 1024*768*2 = 1572864
#define OFF_B1    12651520u     // 2048*4 (pad 8192)
#define OFF_B2    12659712u     // 1024*4 (pad 4096)
#define OFF_FC1W  12663808u     // 128*512*2 = 131072
#define OFF_FC2W  12794880u     // 64*128*2 = 16384
#define OFF_HS2   12811264u     // 64*1024*256*2 = 33554432
#define OFF_HST   46365696u     // 33554432 -> end ~80 MB

__device__ __forceinline__ bf16x8 ld16(const bf16_t* p) {
  u32x4 u = *reinterpret_cast<const u32x4*>(p);
  return __builtin_bit_cast(bf16x8, u);
}
// L2-bypassing (MALL-coherent) 16-byte load as two relaxed agent b64 atomics.
// Emits global_load_dwordx2 with sc0/sc1 -> reads the coherence point, never stale.
__device__ __forceinline__ bf16x8 ld16_mall(const bf16_t* p) {
  u64* q = (u64*)p;
  u64 lo = __hip_atomic_load(q,     __ATOMIC_RELAXED, __HIP_MEMORY_SCOPE_AGENT);
  u64 hi = __hip_atomic_load(q + 1, __ATOMIC_RELAXED, __HIP_MEMORY_SCOPE_AGENT);
  union { u64 q[2]; bf16x8 v; } u;
  u.q[0] = lo; u.q[1] = hi;
  return u.v;
}
// MALL-coherent 8-byte store (4 packed bf16), no cache-maintenance.
__device__ __forceinline__ void st8_mall(bf16_t* p, u64 v) {
  __hip_atomic_store((u64*)p, v, __ATOMIC_RELAXED, __HIP_MEMORY_SCOPE_AGENT);
}
__device__ __forceinline__ f32x4 mfma_bf16(bf16x8 a, bf16x8 b, f32x4 c) {
  return __builtin_amdgcn_mfma_f32_16x16x32_bf16(a, b, c, 0, 0, 0);
}
__device__ __forceinline__ float sigf(float x) { return 1.f / (1.f + __expf(-x)); }
__device__ __forceinline__ float tanh_fast(float x) {
  float e = __expf(-2.f * fabsf(x));
  float r = (1.f - e) / (1.f + e);
  return x < 0.f ? -r : r;
}
__device__ __forceinline__ unsigned short bf16_bits(float v) {
  __hip_bfloat16 b = __float2bfloat16(v);
  return *reinterpret_cast<unsigned short*>(&b);
}

// ---------------- setup: bf16 conversion / packing ----------------
__global__ void setup_kernel(const float* __restrict__ x,
    const float* __restrict__ Wih1, const float* __restrict__ Whh1,
    const float* __restrict__ bih1, const float* __restrict__ bhh1,
    const float* __restrict__ Wih2, const float* __restrict__ Whh2,
    const float* __restrict__ bih2, const float* __restrict__ bhh2,
    const float* __restrict__ fc1w, const float* __restrict__ fc2w,
    char* __restrict__ ws)
{
  bf16_t* xb = (bf16_t*)(ws + OFF_XB);
  bf16_t* w1 = (bf16_t*)(ws + OFF_W1);
  bf16_t* w2 = (bf16_t*)(ws + OFF_W2);
  float*  b1 = (float*)(ws + OFF_B1);
  float*  b2 = (float*)(ws + OFF_B2);
  bf16_t* f1 = (bf16_t*)(ws + OFF_FC1W);
  bf16_t* f2 = (bf16_t*)(ws + OFF_FC2W);
  const long E0 = 4194304, E1 = E0 + 1179648, E2 = E1 + 786432,
             E3 = E2 + 2048, E4 = E3 + 1024, E5 = E4 + 65536, E6 = E5 + 8192;
  for (long i = blockIdx.x * (long)blockDim.x + threadIdx.x; i < E6;
       i += (long)gridDim.x * blockDim.x) {
    if (i < E0) {
      xb[i] = __float2bfloat16(x[i]);
    } else if (i < E1) {                       // W1[j][k] = concat(Wih1, Whh1) rows
      long idx = i - E0; long j = idx / 576, k = idx % 576;
      float v = (k < 64) ? Wih1[j * 64 + k] : Whh1[j * 512 + (k - 64)];
      w1[idx] = __float2bfloat16(v);
    } else if (i < E2) {                       // W2[j][k] = concat(Wih2, Whh2)
      long idx = i - E1; long j = idx / 768, k = idx % 768;
      float v = (k < 512) ? Wih2[j * 512 + k] : Whh2[j * 256 + (k - 512)];
      w2[idx] = __float2bfloat16(v);
    } else if (i < E3) {
      long idx = i - E2; b1[idx] = bih1[idx] + bhh1[idx];
    } else if (i < E4) {
      long idx = i - E3; b2[idx] = bih2[idx] + bhh2[idx];
    } else if (i < E5) {
      long idx = i - E4; f1[idx] = __float2bfloat16(fc1w[idx]);
    } else {                                   // fc2 padded to 64 rows
      long idx = i - E5; long j = idx / 128, k = idx % 128;
      f2[idx] = __float2bfloat16(j < 51 ? fc2w[j * 128 + k] : 0.f);
    }
  }
}

// ---------------- flag sync: relaxed wave-parallel poll (NO acquire/inv) --------
// Data itself travels via MALL-coherent bypass accesses, so no cache-maintenance
// is needed anywhere: polls and publishes are all relaxed agent atomics.
__device__ __forceinline__ void poll_flags(unsigned* f1, unsigned* f2,
                                           int need1, int need2) {
  if (threadIdx.x < 64) {
    const int lane = threadIdx.x;
    unsigned* p = nullptr;
    int need = 0;
    if (lane < NB1)              { p = f1 + lane * 32;         need = need1; }
    else if (lane < NB1 + NB2)   { p = f2 + (lane - NB1) * 32; need = need2; }
    bool ok = (p == nullptr) || (need <= 0);
    if (!ok)
      ok = ((int)__hip_atomic_load(p, __ATOMIC_RELAXED, __HIP_MEMORY_SCOPE_AGENT) >= need);
    while (!__all(ok)) {
      __builtin_amdgcn_s_sleep(1);
      if (p && need > 0)
        ok = ((int)__hip_atomic_load(p, __ATOMIC_RELAXED, __HIP_MEMORY_SCOPE_AGENT) >= need);
      else
        ok = true;
    }
  }
  __syncthreads();
}

__device__ __forceinline__ void publish_flag(unsigned* slot, unsigned gen) {
  // Preceded by __syncthreads() whose structural s_waitcnt vmcnt(0) drains the
  // MALL-acked h stores; relaxed agent store then publishes (no wbl2 walk).
  if (threadIdx.x == 0)
    __hip_atomic_store(slot, gen, __ATOMIC_RELAXED, __HIP_MEMORY_SCOPE_AGENT);
}

// ---------------- persistent LSTM kernel (both layers, MALL-coherent exchange) ----
__global__ __launch_bounds__(256, 1) void lstm_kernel(char* __restrict__ ws,
                                                      float* __restrict__ dout)
{
  const bf16_t* xb  = (const bf16_t*)(ws + OFF_XB);
  const bf16_t* W1  = (const bf16_t*)(ws + OFF_W1);
  const bf16_t* W2  = (const bf16_t*)(ws + OFF_W2);
  const float*  b1  = (const float*)(ws + OFF_B1);
  const float*  b2  = (const float*)(ws + OFF_B2);
  bf16_t* h1b = (bf16_t*)(ws + OFF_H1B);      // 4-deep ring (MALL-coherent)
  bf16_t* h2b = (bf16_t*)(ws + OFF_H2B);      // 2-deep ring (MALL-coherent)
  bf16_t* hs2 = (bf16_t*)(ws + OFF_HS2);
  unsigned* flag1 = (unsigned*)(ws + OFF_BAR);          // 16 x 128 B
  unsigned* flag2 = flag1 + NB1 * 32;                   // 8 x 128 B

  __shared__ float gbuf[4][64][33];   // +1 pad col: conflict-free for both phases

  const int tid  = threadIdx.x;
  const int wave = tid >> 6;
  const int lane = tid & 63;
  const int l15  = lane & 15;
  const int quad = lane >> 4;
  const int wg   = blockIdx.x;
  const f32x4 z = {0.f, 0.f, 0.f, 0.f};

  if (wg < NB1) {
    // ---- LSTM layer 1: block owns 32 units [u0, u0+32), wave = gate
    const int u0 = wg * 32;
    bf16x8 wf[18][2];
    #pragma unroll
    for (int i = 0; i < 18; ++i) {
      int k = (i < 2) ? i * 32 : 64 + (i - 2) * 32;
      #pragma unroll
      for (int nt = 0; nt < 2; ++nt)
        wf[i][nt] = ld16(W1 + (size_t)(wave * H1_ + u0 + nt * 16 + l15) * K1_ + k + quad * 8);
    }
    // per-thread elementwise ownership: 2 x (seq, 4 consecutive units)
    int bb[2], ul[2];
    float bi[2][4], bff[2][4], bg[2][4], bo[2][4], creg[2][4];
    #pragma unroll
    for (int r = 0; r < 2; ++r) {
      int idx = tid + r * 256;          // 0..511
      bb[r] = idx & 63;
      ul[r] = (idx >> 6) * 4;           // 0,4,..,28
      #pragma unroll
      for (int j = 0; j < 4; ++j) {
        int ug = u0 + ul[r] + j;
        bi[r][j]  = b1[ug];
        bff[r][j] = b1[H1_ + ug];
        bg[r][j]  = b1[2 * H1_ + ug];
        bo[r][j]  = b1[3 * H1_ + ug];
        creg[r][j] = 0.f;
      }
    }
    #pragma unroll 1
    for (int t = 0; t < T_; ++t) {
      // x-part first: independent of flags, overlaps poll latency
      f32x4 acc[4][2];
      #pragma unroll
      for (int mt = 0; mt < 4; ++mt) { acc[mt][0] = z; acc[mt][1] = z; }
      #pragma unroll
      for (int ki = 0; ki < 2; ++ki) {
        #pragma unroll
        for (int mt = 0; mt < 4; ++mt) {
          bf16x8 aw = ld16(xb + ((size_t)(mt * 16 + l15) * T_ + t) * IN_ + ki * 32 + quad * 8);
          #pragma unroll
          for (int nt = 0; nt < 2; ++nt)
            acc[mt][nt] = mfma_bf16(aw, wf[ki][nt], acc[mt][nt]);
        }
      }
      // peers' h1(t-1) visible (flag1 >= t); ring slot free (flag2 >= t-3)
      poll_flags(flag1, flag2, t, t - 3);
      const bf16_t* hprev = h1b + ((t - 1) & 3) * (N_ * H1_);
      bf16_t* hcur = h1b + (t & 3) * (N_ * H1_);
      #pragma unroll
      for (int ki = 0; ki < 16; ++ki) {
        #pragma unroll
        for (int mt = 0; mt < 4; ++mt) {
          bf16x8 aw = ld16_mall(hprev + (size_t)(mt * 16 + l15) * H1_ + ki * 32 + quad * 8);
          #pragma unroll
          for (int nt = 0; nt < 2; ++nt)
            acc[mt][nt] = mfma_bf16(aw, wf[2 + ki][nt], acc[mt][nt]);
        }
      }
      #pragma unroll
      for (int mt = 0; mt < 4; ++mt)
        #pragma unroll
        for (int nt = 0; nt < 2; ++nt)
          #pragma unroll
          for (int r = 0; r < 4; ++r)
            gbuf[wave][mt * 16 + quad * 4 + r][nt * 16 + l15] = acc[mt][nt][r];
      __syncthreads();
      #pragma unroll
      for (int r = 0; r < 2; ++r) {
        int b = bb[r], u = ul[r];
        u64 pack = 0;
        float hv[4];
        #pragma unroll
        for (int j = 0; j < 4; ++j) {
          float iv = sigf(gbuf[0][b][u + j] + bi[r][j]);
          float fv = sigf(gbuf[1][b][u + j] + bff[r][j]);
          float gv = tanh_fast(gbuf[2][b][u + j] + bg[r][j]);
          float ov = sigf(gbuf[3][b][u + j] + bo[r][j]);
          float c = fv * creg[r][j] + iv * gv;
          creg[r][j] = c;
          float h = ov * tanh_fast(c);
          hv[j] = h;
          pack |= (u64)bf16_bits(h) << (16 * j);
        }
        st8_mall(hcur + (size_t)b * H1_ + u0 + u, pack);
        if (t == T_ - 1) {
          #pragma unroll
          for (int j = 0; j < 4; ++j) {
            dout[65536 + b * H1_ + u0 + u + j] = hv[j];
            dout[98304 + b * H1_ + u0 + u + j] = creg[r][j];
          }
        }
      }
      __syncthreads();   // drains h stores (vmcnt 0) + protects gbuf reuse
      publish_flag(flag1 + wg * 32, (unsigned)(t + 1));
    }
  } else {
    // ---- LSTM layer 2: block owns 32 units, own t-loop, flag-gated behind L1
    const int wg2 = wg - NB1;
    const int u0 = wg2 * 32;
    bf16x8 wf[24][2];
    #pragma unroll
    for (int i = 0; i < 24; ++i) {
      int k = (i < 16) ? i * 32 : 512 + (i - 16) * 32;
      #pragma unroll
      for (int nt = 0; nt < 2; ++nt)
        wf[i][nt] = ld16(W2 + (size_t)(wave * H2_ + u0 + nt * 16 + l15) * K2_ + k + quad * 8);
    }
    int bb[2], ul[2];
    float bi[2][4], bff[2][4], bg[2][4], bo[2][4], creg[2][4];
    #pragma unroll
    for (int r = 0; r < 2; ++r) {
      int idx = tid + r * 256;
      bb[r] = idx & 63;
      ul[r] = (idx >> 6) * 4;
      #pragma unroll
      for (int j = 0; j < 4; ++j) {
        int ug = u0 + ul[r] + j;
        bi[r][j]  = b2[ug];
        bff[r][j] = b2[H2_ + ug];
        bg[r][j]  = b2[2 * H2_ + ug];
        bo[r][j]  = b2[3 * H2_ + ug];
        creg[r][j] = 0.f;
      }
    }
    #pragma unroll 1
    for (int t = 0; t < T_; ++t) {
      // h1(t) published (flag1 >= t+1); peers' h2(t-1) visible (flag2 >= t)
      poll_flags(flag1, flag2, t + 1, t);
      const bf16_t* xin   = h1b + (t & 3) * (N_ * H1_);
      const bf16_t* hprev = h2b + ((t - 1) & 1) * (N_ * H2_);
      bf16_t* hcur = h2b + (t & 1) * (N_ * H2_);
      f32x4 acc[4][2];
      #pragma unroll
      for (int mt = 0; mt < 4; ++mt) { acc[mt][0] = z; acc[mt][1] = z; }
      #pragma unroll
      for (int ki = 0; ki < 16; ++ki) {
        #pragma unroll
        for (int mt = 0; mt < 4; ++mt) {
          bf16x8 aw = ld16_mall(xin + (size_t)(mt * 16 + l15) * H1_ + ki * 32 + quad * 8);
          #pragma unroll
          for (int nt = 0; nt < 2; ++nt)
            acc[mt][nt] = mfma_bf16(aw, wf[ki][nt], acc[mt][nt]);
        }
      }
      #pragma unroll
      for (int ki = 0; ki < 8; ++ki) {
        #pragma unroll
        for (int mt = 0; mt < 4; ++mt) {
          bf16x8 aw = ld16_mall(hprev + (size_t)(mt * 16 + l15) * H2_ + ki * 32 + quad * 8);
          #pragma unroll
          for (int nt = 0; nt < 2; ++nt)
            acc[mt][nt] = mfma_bf16(aw, wf[16 + ki][nt], acc[mt][nt]);
        }
      }
      #pragma unroll
      for (int mt = 0; mt < 4; ++mt)
        #pragma unroll
        for (int nt = 0; nt < 2; ++nt)
          #pragma unroll
          for (int r = 0; r < 4; ++r)
            gbuf[wave][mt * 16 + quad * 4 + r][nt * 16 + l15] = acc[mt][nt][r];
      __syncthreads();
      #pragma unroll
      for (int r = 0; r < 2; ++r) {
        int b = bb[r], u = ul[r];
        u64 pack = 0;
        float hv[4];
        #pragma unroll
        for (int j = 0; j < 4; ++j) {
          float iv = sigf(gbuf[0][b][u + j] + bi[r][j]);
          float fv = sigf(gbuf[1][b][u + j] + bff[r][j]);
          float gv = tanh_fast(gbuf[2][b][u + j] + bg[r][j]);
          float ov = sigf(gbuf[3][b][u + j] + bo[r][j]);
          float c = fv * creg[r][j] + iv * gv;
          creg[r][j] = c;
          float h = ov * tanh_fast(c);
          hv[j] = h;
          pack |= (u64)bf16_bits(h) << (16 * j);
        }
        st8_mall(hcur + (size_t)b * H2_ + u0 + u, pack);
        *reinterpret_cast<u64*>(hs2 + ((size_t)b * T_ + t) * H2_ + u0 + u) = pack;  // cached
        if (t == T_ - 1) {
          #pragma unroll
          for (int j = 0; j < 4; ++j) {
            dout[131072 + b * H2_ + u0 + u + j] = hv[j];
            dout[147456 + b * H2_ + u0 + u + j] = creg[r][j];
          }
        }
      }
      __syncthreads();
      publish_flag(flag2 + wg2 * 32, (unsigned)(t + 1));
    }
  }
}

// ---------------- hs2 [n][t][ch] -> hsT [n][ch][t]  (LDS tile transpose) ----------------
__global__ __launch_bounds__(256) void transpose_kernel(char* __restrict__ ws)
{
  const unsigned short* src = (const unsigned short*)(ws + OFF_HS2);
  unsigned short* dst = (unsigned short*)(ws + OFF_HST);
  __shared__ unsigned short tile[64][72];
  const int bx = blockIdx.x;
  const int n  = bx >> 6;
  const int tt = (bx & 63) >> 2;
  const int cb = bx & 3;
  const int t0 = tt * 64, c0 = cb * 64;
  const int tid = threadIdx.x;
  const int row = tid >> 3;          // 0..31
  const int colg = (tid & 7) * 8;    // 0,8,..,56
  #pragma unroll
  for (int i = 0; i < 2; ++i) {
    int r = row + i * 32;
    u16x8 v = *reinterpret_cast<const u16x8*>(src + ((size_t)n * T_ + t0 + r) * H2_ + c0 + colg);
    *reinterpret_cast<u16x8*>(&tile[r][colg]) = v;
  }
  __syncthreads();
  #pragma unroll
  for (int i = 0; i < 2; ++i) {
    int crow = row + i * 32;
    u16x8 v;
    #pragma unroll
    for (int j = 0; j < 8; ++j) v[j] = tile[colg + j][crow];
    *reinterpret_cast<u16x8*>(dst + ((size_t)n * H2_ + c0 + crow) * T_ + t0 + colg) = v;
  }
}

// ---------------- flash attention + fused FC head ----------------
__global__ __launch_bounds__(256, 2) void attn_fc_kernel(
    const char* __restrict__ ws,
    const float* __restrict__ fc1b, const float* __restrict__ fc2b,
    const float* __restrict__ fc3w, const float* __restrict__ fc3b,
    float* __restrict__ dout)
{
  const bf16_t* hs2 = (const bf16_t*)(ws + OFF_HS2);
  const bf16_t* hsT = (const bf16_t*)(ws + OFF_HST);
  const bf16_t* f1w = (const bf16_t*)(ws + OFF_FC1W);
  const bf16_t* f2w = (const bf16_t*)(ws + OFF_FC2W);

  __shared__ __align__(16) unsigned char smem[51200];
  bf16_t* ctxlds = (bf16_t*)smem;             // [64][264]
  bf16_t* act1   = (bf16_t*)(smem + 33792);   // [64][136]
  bf16_t* plds   = (bf16_t*)(smem + 33792);   // wave w: +w*1152, [16][72]
  float*  act2   = (float*)smem;              // [64][68]

  const int tid  = threadIdx.x;
  const int wave = tid >> 6, lane = tid & 63;
  const int l15  = lane & 15, quad = lane >> 4;
  const int n  = blockIdx.x >> 4;
  const int qt = blockIdx.x & 15;
  const int q0 = qt * 64;
  const f32x4 z = {0.f, 0.f, 0.f, 0.f};

  bf16x8 aq[8];
  #pragma unroll
  for (int ks = 0; ks < 8; ++ks)
    aq[ks] = ld16(hs2 + ((size_t)n * T_ + q0 + wave * 16 + l15) * H2_ + ks * 32 + quad * 8);

  f32x4 o[16];
  #pragma unroll
  for (int ct = 0; ct < 16; ++ct) o[ct] = z;
  float m_run[4], l_run[4];
  #pragma unroll
  for (int r = 0; r < 4; ++r) { m_run[r] = -1e30f; l_run[r] = 0.f; }

  bf16_t* pw = plds + wave * 1152;

  #pragma unroll 1
  for (int st = 0; st <= qt; ++st) {
    const int s0 = st * 64;
    f32x4 sc[4] = {z, z, z, z};
    #pragma unroll
    for (int ks = 0; ks < 8; ++ks) {
      #pragma unroll
      for (int nt = 0; nt < 4; ++nt) {
        bf16x8 bk = ld16(hs2 + ((size_t)n * T_ + s0 + nt * 16 + l15) * H2_ + ks * 32 + quad * 8);
        sc[nt] = mfma_bf16(aq[ks], bk, sc[nt]);
      }
    }
    if (st == qt) {
      int qg = q0 + wave * 16 + quad * 4;
      #pragma unroll
      for (int nt = 0; nt < 4; ++nt) {
        int sg = s0 + nt * 16 + l15;
        #pragma unroll
        for (int r = 0; r < 4; ++r)
          if (sg > qg + r) sc[nt][r] = -1e30f;
      }
    }
    float alpha[4];
    #pragma unroll
    for (int r = 0; r < 4; ++r) {
      float tm = fmaxf(fmaxf(sc[0][r], sc[1][r]), fmaxf(sc[2][r], sc[3][r]));
      tm = fmaxf(tm, __shfl_xor(tm, 1, 16));
      tm = fmaxf(tm, __shfl_xor(tm, 2, 16));
      tm = fmaxf(tm, __shfl_xor(tm, 4, 16));
      tm = fmaxf(tm, __shfl_xor(tm, 8, 16));
      float mnew = fmaxf(m_run[r], tm);
      alpha[r] = __expf(m_run[r] - mnew);
      m_run[r] = mnew;
      float ts = 0.f;
      #pragma unroll
      for (int nt = 0; nt < 4; ++nt) {
        float p = __expf(sc[nt][r] - mnew);
        sc[nt][r] = p;
        ts += p;
      }
      ts += __shfl_xor(ts, 1, 16);
      ts += __shfl_xor(ts, 2, 16);
      ts += __shfl_xor(ts, 4, 16);
      ts += __shfl_xor(ts, 8, 16);
      l_run[r] = l_run[r] * alpha[r] + ts;
    }
    #pragma unroll
    for (int ct = 0; ct < 16; ++ct)
      #pragma unroll
      for (int r = 0; r < 4; ++r)
        o[ct][r] *= alpha[r];
    #pragma unroll
    for (int nt = 0; nt < 4; ++nt)
      #pragma unroll
      for (int r = 0; r < 4; ++r)
        pw[(quad * 4 + r) * 72 + nt * 16 + l15] = __float2bfloat16(sc[nt][r]);
    #pragma unroll
    for (int ks2 = 0; ks2 < 2; ++ks2) {
      bf16x8 ap = ld16(pw + l15 * 72 + ks2 * 32 + quad * 8);
      #pragma unroll
      for (int ct = 0; ct < 16; ++ct) {
        bf16x8 bv = ld16(hsT + ((size_t)n * H2_ + ct * 16 + l15) * T_ + s0 + ks2 * 32 + quad * 8);
        o[ct] = mfma_bf16(ap, bv, o[ct]);
      }
    }
  }
  float inv[4];
  #pragma unroll
  for (int r = 0; r < 4; ++r) inv[r] = 1.f / l_run[r];
  #pragma unroll
  for (int ct = 0; ct < 16; ++ct)
    #pragma unroll
    for (int r = 0; r < 4; ++r)
      ctxlds[(wave * 16 + quad * 4 + r) * 264 + ct * 16 + l15] =
          __float2bfloat16(o[ct][r] * inv[r]);
  __syncthreads();

  // fc1: K=512 (ctx|hs2) -> 128 ch, wave owns 32 channels
  f32x4 a1[4][2];
  #pragma unroll
  for (int mt = 0; mt < 4; ++mt) { a1[mt][0] = z; a1[mt][1] = z; }
  #pragma unroll
  for (int ks = 0; ks < 16; ++ks) {
    bf16x8 af[4];
    if (ks < 8) {
      #pragma unroll
      for (int mt = 0; mt < 4; ++mt)
        af[mt] = ld16(ctxlds + (mt * 16 + l15) * 264 + ks * 32 + quad * 8);
    } else {
      #pragma unroll
      for (int mt = 0; mt < 4; ++mt)
        af[mt] = ld16(hs2 + ((size_t)n * T_ + q0 + mt * 16 + l15) * H2_ + (ks - 8) * 32 + quad * 8);
    }
    #pragma unroll
    for (int nt = 0; nt < 2; ++nt) {
      bf16x8 bw = ld16(f1w + (size_t)(wave * 32 + nt * 16 + l15) * 512 + ks * 32 + quad * 8);
      #pragma unroll
      for (int mt = 0; mt < 4; ++mt)
        a1[mt][nt] = mfma_bf16(af[mt], bw, a1[mt][nt]);
    }
  }
  #pragma unroll
  for (int mt = 0; mt < 4; ++mt)
    #pragma unroll
    for (int nt = 0; nt < 2; ++nt)
      #pragma unroll
      for (int r = 0; r < 4; ++r) {
        int ch = wave * 32 + nt * 16 + l15;
        float v = a1[mt][nt][r] + fc1b[ch];
        act1[(mt * 16 + quad * 4 + r) * 136 + ch] = __float2bfloat16(fmaxf(v, 0.f));
      }
  __syncthreads();

  // fc2: K=128 -> 51 ch (padded 64), wave owns 16 channels
  f32x4 a2[4] = {z, z, z, z};
  #pragma unroll
  for (int ks = 0; ks < 4; ++ks) {
    bf16x8 bw = ld16(f2w + (wave * 16 + l15) * 128 + ks * 32 + quad * 8);
    #pragma unroll
    for (int mt = 0; mt < 4; ++mt) {
      bf16x8 af = ld16(act1 + (mt * 16 + l15) * 136 + ks * 32 + quad * 8);
      a2[mt] = mfma_bf16(af, bw, a2[mt]);
    }
  }
  #pragma unroll
  for (int mt = 0; mt < 4; ++mt)
    #pragma unroll
    for (int r = 0; r < 4; ++r) {
      int ch = wave * 16 + l15;
      int row = mt * 16 + quad * 4 + r;
      float v = a2[mt][r] + (ch < 51 ? fc2b[ch] : 0.f);
      act2[row * 68 + ch] = fmaxf(v, 0.f);
    }
  __syncthreads();

  // fc3: dot over 51
  if (tid < 64) {
    float s = fc3b[0];
    for (int c = 0; c < 51; ++c) s += act2[tid * 68 + c] * fc3w[c];
    dout[(size_t)n * T_ + q0 + tid] = s;
  }
}

extern "C" void kernel_launch(void* const* d_in, const int* in_sizes, int n_in,
                              void* d_out, int out_size, void* d_ws, size_t ws_size,
                              hipStream_t stream) {
  (void)in_sizes; (void)n_in; (void)out_size; (void)ws_size;
  const float* x    = (const float*)d_in[0];
  const float* Wih1 = (const float*)d_in[1];
  const float* Whh1 = (const float*)d_in[2];
  const float* bih1 = (const float*)d_in[3];
  const float* bhh1 = (const float*)d_in[4];
  const float* Wih2 = (const float*)d_in[5];
  const float* Whh2 = (const float*)d_in[6];
  const float* bih2 = (const float*)d_in[7];
  const float* bhh2 = (const float*)d_in[8];
  const float* fc1w = (const float*)d_in[9];
  const float* fc1b = (const float*)d_in[10];
  const float* fc2w = (const float*)d_in[11];
  const float* fc2b = (const float*)d_in[12];
  const float* fc3w = (const float*)d_in[13];
  const float* fc3b = (const float*)d_in[14];
  char* ws  = (char*)d_ws;
  float* out = (float*)d_out;

  hipMemsetAsync(ws, 0, ZERO_BYTES, stream);   // h rings + flags
  setup_kernel<<<2048, 256, 0, stream>>>(x, Wih1, Whh1, bih1, bhh1,
                                         Wih2, Whh2, bih2, bhh2, fc1w, fc2w, ws);
  lstm_kernel<<<NBLK, 256, 0, stream>>>(ws, out);
  transpose_kernel<<<4096, 256, 0, stream>>>(ws);
  attn_fc_kernel<<<1024, 256, 0, stream>>>(ws, fc1b, fc2b, fc3w, fc3b, out);
}

// Round 6
// 3798.461 us; speedup vs baseline: 7.0414x; 7.0414x over previous
//
#include <hip/hip_runtime.h>
#include <hip/hip_bf16.h>

#define N_   64
#define T_   1024
#define IN_  64
#define H1_  512
#define H2_  256
#define NG   4      // batch groups of 16 rows
#define NU1  16     // layer-1 unit-blocks per group (32 units each)
#define NU2  8      // layer-2 unit-blocks per group (32 units each)
#define RING 8      // h1 ring depth (per group)

typedef __bf16 bf16x8 __attribute__((ext_vector_type(8)));
typedef float  f32x4  __attribute__((ext_vector_type(4)));
typedef unsigned int u32x4 __attribute__((ext_vector_type(4)));
typedef unsigned short u16x8 __attribute__((ext_vector_type(8)));
typedef unsigned long long u64;
typedef __hip_bfloat16 bf16_t;

// ---------------- workspace layout (bytes) ----------------
#define OFF_FLG1  0u          // 4*16*128 = 8192
#define OFF_FLG2  8192u       // 4*8*128  = 4096
#define OFF_QUE   12288u      // work-queue counter
#define ZERO_BYTES 16384u
#define OFF_H1R   16384u      // h1 ring: 4g*8slot*16row*512*2 = 524288
#define OFF_XB    540672u     // 8388608
#define OFF_W1    8929280u    // 2048*576*2 = 2359296
#define OFF_W2    11288576u   // 1024*768*2 = 1572864
#define OFF_B1    12861440u   // 8192
#define OFF_B2    12869632u   // 4096
#define OFF_FC1W  12873728u   // 131072
#define OFF_FC2W  13004800u   // 16384
#define OFF_HS2   13021184u   // 64*1024*256*2 = 33554432
#define OFF_BURN  46575616u   // dummy sink (never actually written)

__device__ __forceinline__ bf16x8 ld16(const bf16_t* p) {
  u32x4 u = *reinterpret_cast<const u32x4*>(p);
  return __builtin_bit_cast(bf16x8, u);
}
// MALL-coherent (L2-bypass) 16B load: two relaxed agent b64 atomics
__device__ __forceinline__ bf16x8 ld16_mall(const bf16_t* p) {
  u64* q = (u64*)p;
  u64 lo = __hip_atomic_load(q,     __ATOMIC_RELAXED, __HIP_MEMORY_SCOPE_AGENT);
  u64 hi = __hip_atomic_load(q + 1, __ATOMIC_RELAXED, __HIP_MEMORY_SCOPE_AGENT);
  union { u64 q[2]; bf16x8 v; } u;
  u.q[0] = lo; u.q[1] = hi;
  return u.v;
}
// MALL-coherent 4-B store (2 packed bf16), write-through, no cache walks
__device__ __forceinline__ void st4_mall(bf16_t* p, unsigned v) {
  __hip_atomic_store((unsigned*)p, v, __ATOMIC_RELAXED, __HIP_MEMORY_SCOPE_AGENT);
}
__device__ __forceinline__ f32x4 mfma_bf16(bf16x8 a, bf16x8 b, f32x4 c) {
  return __builtin_amdgcn_mfma_f32_16x16x32_bf16(a, b, c, 0, 0, 0);
}
__device__ __forceinline__ float sigf(float x) { return 1.f / (1.f + __expf(-x)); }
__device__ __forceinline__ float tanh_fast(float x) {
  float e = __expf(-2.f * fabsf(x));
  float r = (1.f - e) / (1.f + e);
  return x < 0.f ? -r : r;
}
__device__ __forceinline__ unsigned short bf16_bits(float v) {
  __hip_bfloat16 b = __float2bfloat16(v);
  return *reinterpret_cast<unsigned short*>(&b);
}

// ---------------- setup: bf16 conversion / packing ----------------
__global__ void setup_kernel(const float* __restrict__ x,
    const float* __restrict__ Wih1, const float* __restrict__ Whh1,
    const float* __restrict__ bih1, const float* __restrict__ bhh1,
    const float* __restrict__ Wih2, const float* __restrict__ Whh2,
    const float* __restrict__ bih2, const float* __restrict__ bhh2,
    const float* __restrict__ fc1w, const float* __restrict__ fc2w,
    char* __restrict__ ws)
{
  bf16_t* xb = (bf16_t*)(ws + OFF_XB);
  bf16_t* w1 = (bf16_t*)(ws + OFF_W1);
  bf16_t* w2 = (bf16_t*)(ws + OFF_W2);
  float*  b1 = (float*)(ws + OFF_B1);
  float*  b2 = (float*)(ws + OFF_B2);
  bf16_t* f1 = (bf16_t*)(ws + OFF_FC1W);
  bf16_t* f2 = (bf16_t*)(ws + OFF_FC2W);
  const long E0 = 4194304, E1 = E0 + 1179648, E2 = E1 + 786432,
             E3 = E2 + 2048, E4 = E3 + 1024, E5 = E4 + 65536, E6 = E5 + 8192;
  for (long i = blockIdx.x * (long)blockDim.x + threadIdx.x; i < E6;
       i += (long)gridDim.x * blockDim.x) {
    if (i < E0) {
      xb[i] = __float2bfloat16(x[i]);
    } else if (i < E1) {                       // W1[j][k] = [Wih1 | Whh1]
      long idx = i - E0; long j = idx / 576, k = idx % 576;
      float v = (k < 64) ? Wih1[j * 64 + k] : Whh1[j * 512 + (k - 64)];
      w1[idx] = __float2bfloat16(v);
    } else if (i < E2) {                       // W2[j][k] = [Wih2 | Whh2]
      long idx = i - E1; long j = idx / 768, k = idx % 768;
      float v = (k < 512) ? Wih2[j * 512 + k] : Whh2[j * 256 + (k - 512)];
      w2[idx] = __float2bfloat16(v);
    } else if (i < E3) {
      long idx = i - E2; b1[idx] = bih1[idx] + bhh1[idx];
    } else if (i < E4) {
      long idx = i - E3; b2[idx] = bih2[idx] + bhh2[idx];
    } else if (i < E5) {
      long idx = i - E4; f1[idx] = __float2bfloat16(fc1w[idx]);
    } else {                                   // fc2 padded to 64 rows
      long idx = i - E5; long j = idx / 128, k = idx % 128;
      f2[idx] = __float2bfloat16(j < 51 ? fc2w[j * 128 + k] : 0.f);
    }
  }
}

// relaxed wave-parallel poll of two flag sets, then block sync
__device__ __forceinline__ void poll2(unsigned* fA, int cntA, int needA,
                                      unsigned* fB, int cntB, int needB) {
  if (threadIdx.x < 64) {
    const int lane = threadIdx.x;
    unsigned* p = nullptr; int need = 0;
    if (lane < cntA)             { p = fA + lane * 32;          need = needA; }
    else if (lane < cntA + cntB) { p = fB + (lane - cntA) * 32; need = needB; }
    bool ok = (p == nullptr) || (need <= 0) ||
      ((int)__hip_atomic_load(p, __ATOMIC_RELAXED, __HIP_MEMORY_SCOPE_AGENT) >= need);
    while (!__all(ok)) {
      __builtin_amdgcn_s_sleep(1);
      ok = (p == nullptr) || (need <= 0) ||
        ((int)__hip_atomic_load(p, __ATOMIC_RELAXED, __HIP_MEMORY_SCOPE_AGENT) >= need);
    }
  }
  __syncthreads();
}

// ============================================================================
// fused persistent kernel: 64 L1 + 32 L2 + 160 attention workers = 256 blocks
// ============================================================================
__global__ __launch_bounds__(256, 1) void fused_kernel(char* __restrict__ ws,
    const float* __restrict__ fc1b, const float* __restrict__ fc2b,
    const float* __restrict__ fc3w, const float* __restrict__ fc3b,
    float* __restrict__ dout)
{
  const bf16_t* xb  = (const bf16_t*)(ws + OFF_XB);
  const bf16_t* W1  = (const bf16_t*)(ws + OFF_W1);
  const bf16_t* W2  = (const bf16_t*)(ws + OFF_W2);
  const float*  b1  = (const float*)(ws + OFF_B1);
  const float*  b2  = (const float*)(ws + OFF_B2);
  bf16_t* h1r = (bf16_t*)(ws + OFF_H1R);
  bf16_t* hs2 = (bf16_t*)(ws + OFF_HS2);
  unsigned* flag1 = (unsigned*)(ws + OFF_FLG1);   // [g][u1] stride 32 words
  unsigned* flag2 = (unsigned*)(ws + OFF_FLG2);   // [g][u2]

  __shared__ __align__(16) char smem[55296];

  const int tid  = threadIdx.x;
  const int wave = tid >> 6;
  const int lane = tid & 63;
  const int l15  = lane & 15;
  const int quad = lane >> 4;
  const int bx   = blockIdx.x;
  const f32x4 z = {0.f, 0.f, 0.f, 0.f};

  if (bx < NG * NU1) {
    // ================= LSTM layer 1 block: group g, units [u0,u0+32) ========
    const int g = bx >> 4, u = bx & 15, u0 = u * 32;
    bf16_t* hstage = (bf16_t*)smem;                 // [16][584] x|h concat
    float*  gbuf   = (float*)(smem + 18688);        // [4][16][33]
    bf16x8 wf[18][2];
    #pragma unroll
    for (int i = 0; i < 18; ++i)
      #pragma unroll
      for (int nt = 0; nt < 2; ++nt)
        wf[i][nt] = ld16(W1 + (size_t)(wave * H1_ + u0 + nt * 16 + l15) * 576 + i * 32 + quad * 8);

    const int row = tid >> 4;          // 0..15 (batch row in group)
    const int ui  = (tid & 15) * 2;    // 0..30 (unit pair)
    const int nrow = g * 16 + row;
    float bi[2], bff[2], bg[2], bo[2], creg[2];
    #pragma unroll
    for (int j = 0; j < 2; ++j) {
      int ug = u0 + ui + j;
      bi[j]  = b1[ug];        bff[j] = b1[H1_ + ug];
      bg[j]  = b1[2*H1_ + ug]; bo[j] = b1[3*H1_ + ug];
      creg[j] = 0.f;
    }
    const int sr = tid >> 4, sc4 = (tid & 15) * 4, sc32 = (tid & 15) * 32;

    #pragma unroll 1
    for (int t = 0; t < T_; ++t) {
      // peers' h1(t-1) ready; ring slot t&7 free (L2 consumed t-8)
      poll2(flag1 + g * NU1 * 32, NU1, t, flag2 + g * NU2 * 32, NU2, t - 7);
      // stage x_t and h1(t-1) into LDS (once per block, shared by 4 waves)
      {
        u64 xv = *(const u64*)(xb + ((size_t)(g*16 + sr) * T_ + t) * IN_ + sc4);
        *(u64*)(hstage + sr * 584 + sc4) = xv;
        if (t == 0) {
          #pragma unroll
          for (int k = 0; k < 8; ++k)
            *(u64*)(hstage + sr * 584 + 64 + sc32 + k * 4) = 0ull;
        } else {
          const bf16_t* src = h1r + ((size_t)(g * RING + ((t-1) & 7)) * 16 + sr) * 512 + sc32;
          #pragma unroll
          for (int k = 0; k < 4; ++k) {
            bf16x8 v = ld16_mall(src + k * 8);
            *(bf16x8*)(hstage + sr * 584 + 64 + sc32 + k * 8) = v;
          }
        }
      }
      __syncthreads();
      f32x4 acc[2] = {z, z};
      #pragma unroll
      for (int ki = 0; ki < 18; ++ki) {
        bf16x8 aw = ld16(hstage + l15 * 584 + ki * 32 + quad * 8);
        acc[0] = mfma_bf16(aw, wf[ki][0], acc[0]);
        acc[1] = mfma_bf16(aw, wf[ki][1], acc[1]);
      }
      #pragma unroll
      for (int nt = 0; nt < 2; ++nt)
        #pragma unroll
        for (int r = 0; r < 4; ++r)
          gbuf[(wave * 16 + quad * 4 + r) * 33 + nt * 16 + l15] = acc[nt][r];
      __syncthreads();
      {
        unsigned pack = 0;
        float hv[2];
        #pragma unroll
        for (int j = 0; j < 2; ++j) {
          int col = ui + j;
          float iv = sigf(gbuf[(0*16 + row) * 33 + col] + bi[j]);
          float fv = sigf(gbuf[(1*16 + row) * 33 + col] + bff[j]);
          float gv = tanh_fast(gbuf[(2*16 + row) * 33 + col] + bg[j]);
          float ov = sigf(gbuf[(3*16 + row) * 33 + col] + bo[j]);
          float c = fv * creg[j] + iv * gv;
          creg[j] = c;
          float h = ov * tanh_fast(c);
          hv[j] = h;
          pack |= (unsigned)bf16_bits(h) << (16 * j);
        }
        st4_mall(h1r + ((size_t)(g * RING + (t & 7)) * 16 + row) * 512 + u0 + ui, pack);
        if (t == T_ - 1) {
          #pragma unroll
          for (int j = 0; j < 2; ++j) {
            dout[65536 + nrow * H1_ + u0 + ui + j] = hv[j];
            dout[98304 + nrow * H1_ + u0 + ui + j] = creg[j];
          }
        }
      }
      __syncthreads();   // vmcnt(0): h stores MALL-acked before flag
      if (tid == 0)
        __hip_atomic_store(flag1 + (g * NU1 + u) * 32, (unsigned)(t + 1),
                           __ATOMIC_RELAXED, __HIP_MEMORY_SCOPE_AGENT);
    }
  } else if (bx < NG * NU1 + NG * NU2) {
    // ================= LSTM layer 2 block: group g, units [u0,u0+32) ========
    const int b2x = bx - NG * NU1;
    const int g = b2x >> 3, u = b2x & 7, u0 = u * 32;
    bf16_t* hstage = (bf16_t*)smem;                 // [16][784] h1|h2 concat
    float*  gbuf   = (float*)(smem + 25088);        // [4][16][33]
    bf16x8 wf[24][2];
    #pragma unroll
    for (int i = 0; i < 24; ++i)
      #pragma unroll
      for (int nt = 0; nt < 2; ++nt)
        wf[i][nt] = ld16(W2 + (size_t)(wave * H2_ + u0 + nt * 16 + l15) * 768 + i * 32 + quad * 8);

    const int row = tid >> 4, ui = (tid & 15) * 2;
    const int nrow = g * 16 + row;
    float bi[2], bff[2], bg[2], bo[2], creg[2];
    #pragma unroll
    for (int j = 0; j < 2; ++j) {
      int ug = u0 + ui + j;
      bi[j]  = b2[ug];         bff[j] = b2[H2_ + ug];
      bg[j]  = b2[2*H2_ + ug]; bo[j]  = b2[3*H2_ + ug];
      creg[j] = 0.f;
    }
    const int sr = tid >> 4, sc32 = (tid & 15) * 32, sc16 = (tid & 15) * 16;

    #pragma unroll 1
    for (int t = 0; t < T_; ++t) {
      // h1(t) published by all 16 producers; peers' h2(t-1) ready
      poll2(flag1 + g * NU1 * 32, NU1, t + 1, flag2 + g * NU2 * 32, NU2, t);
      {
        const bf16_t* s1 = h1r + ((size_t)(g * RING + (t & 7)) * 16 + sr) * 512 + sc32;
        #pragma unroll
        for (int k = 0; k < 4; ++k) {
          bf16x8 v = ld16_mall(s1 + k * 8);
          *(bf16x8*)(hstage + sr * 784 + sc32 + k * 8) = v;
        }
        if (t == 0) {
          #pragma unroll
          for (int k = 0; k < 4; ++k)
            *(u64*)(hstage + sr * 784 + 512 + sc16 + k * 4) = 0ull;
        } else {
          const bf16_t* s2 = hs2 + ((size_t)(g*16 + sr) * T_ + (t - 1)) * H2_ + sc16;
          #pragma unroll
          for (int k = 0; k < 2; ++k) {
            bf16x8 v = ld16_mall(s2 + k * 8);
            *(bf16x8*)(hstage + sr * 784 + 512 + sc16 + k * 8) = v;
          }
        }
      }
      __syncthreads();
      f32x4 acc[2] = {z, z};
      #pragma unroll
      for (int ki = 0; ki < 24; ++ki) {
        bf16x8 aw = ld16(hstage + l15 * 784 + ki * 32 + quad * 8);
        acc[0] = mfma_bf16(aw, wf[ki][0], acc[0]);
        acc[1] = mfma_bf16(aw, wf[ki][1], acc[1]);
      }
      #pragma unroll
      for (int nt = 0; nt < 2; ++nt)
        #pragma unroll
        for (int r = 0; r < 4; ++r)
          gbuf[(wave * 16 + quad * 4 + r) * 33 + nt * 16 + l15] = acc[nt][r];
      __syncthreads();
      {
        unsigned pack = 0;
        float hv[2];
        #pragma unroll
        for (int j = 0; j < 2; ++j) {
          int col = ui + j;
          float iv = sigf(gbuf[(0*16 + row) * 33 + col] + bi[j]);
          float fv = sigf(gbuf[(1*16 + row) * 33 + col] + bff[j]);
          float gv = tanh_fast(gbuf[(2*16 + row) * 33 + col] + bg[j]);
          float ov = sigf(gbuf[(3*16 + row) * 33 + col] + bo[j]);
          float c = fv * creg[j] + iv * gv;
          creg[j] = c;
          float h = ov * tanh_fast(c);
          hv[j] = h;
          pack |= (unsigned)bf16_bits(h) << (16 * j);
        }
        st4_mall(hs2 + ((size_t)nrow * T_ + t) * H2_ + u0 + ui, pack);
        if (t == T_ - 1) {
          #pragma unroll
          for (int j = 0; j < 2; ++j) {
            dout[131072 + nrow * H2_ + u0 + ui + j] = hv[j];
            dout[147456 + nrow * H2_ + u0 + ui + j] = creg[j];
          }
        }
      }
      __syncthreads();
      if (tid == 0)
        __hip_atomic_store(flag2 + (g * NU2 + u) * 32, (unsigned)(t + 1),
                           __ATOMIC_RELAXED, __HIP_MEMORY_SCOPE_AGENT);
    }
  } else {
    // ================= attention + FC worker =================================
    const bf16_t* f1w = (const bf16_t*)(ws + OFF_FC1W);
    const bf16_t* f2w = (const bf16_t*)(ws + OFF_FC2W);
    unsigned* queue = (unsigned*)(ws + OFF_QUE);
    unsigned short* vtile = (unsigned short*)smem;     // [256][72] during s-loop
    bf16_t* plds   = (bf16_t*)(smem + 36864);          // wave w: +w*1152, [16][72]
    bf16_t* ctxlds = (bf16_t*)smem;                    // [64][264] post-loop
    bf16_t* act1   = (bf16_t*)(smem + 36864);          // [64][136]
    float*  act2   = (float*)smem;                     // [64][68]
    volatile int* itemslot = (volatile int*)(smem + 55040);
    float burn = 1.0f;

    for (;;) {
      if (tid == 0) *itemslot = (int)atomicAdd(queue, 1u);
      __syncthreads();
      const int item = *itemslot;
      if (item >= 1024) break;
      const int qt = item >> 6, n = item & 63, q0 = qt * 64, gg = n >> 4;

      // wait for hs2[n][0 .. q0+63] (all 8 unit-producers of group gg), with burn
      {
        const int need = q0 + 64;
        if (tid < 64) {
          unsigned* p = (lane < NU2) ? flag2 + (gg * NU2 + lane) * 32 : nullptr;
          bool ok = (p == nullptr) ||
            ((int)__hip_atomic_load(p, __ATOMIC_RELAXED, __HIP_MEMORY_SCOPE_AGENT) >= need);
          while (!__all(ok)) {
            #pragma unroll
            for (int k = 0; k < 32; ++k) burn = fmaf(burn, 1.0000001f, 1e-7f);
            ok = (p == nullptr) ||
              ((int)__hip_atomic_load(p, __ATOMIC_RELAXED, __HIP_MEMORY_SCOPE_AGENT) >= need);
          }
        }
        __syncthreads();
      }

      bf16x8 aq[8];
      #pragma unroll
      for (int ks = 0; ks < 8; ++ks)
        aq[ks] = ld16(hs2 + ((size_t)n * T_ + q0 + wave * 16 + l15) * H2_ + ks * 32 + quad * 8);
      f32x4 o[16];
      #pragma unroll
      for (int ct = 0; ct < 16; ++ct) o[ct] = z;
      float m_run[4], l_run[4];
      #pragma unroll
      for (int r = 0; r < 4; ++r) { m_run[r] = -1e30f; l_run[r] = 0.f; }
      bf16_t* pw = plds + wave * 1152;

      #pragma unroll 1
      for (int st = 0; st <= qt; ++st) {
        const int s0 = st * 64;
        __syncthreads();    // vtile reuse safe
        // stage V-tile transposed: vtile[ch][s]
        #pragma unroll
        for (int it = 0; it < 8; ++it) {
          int s  = (tid >> 3) + (it & 1) * 32;
          int c0 = (tid & 7) * 8 + (it >> 1) * 64;
          u16x8 v = *reinterpret_cast<const u16x8*>(
              (const unsigned short*)hs2 + ((size_t)n * T_ + s0 + s) * H2_ + c0);
          #pragma unroll
          for (int j = 0; j < 8; ++j)
            vtile[(c0 + j) * 72 + s] = v[j];
        }
        __syncthreads();
        f32x4 sc[4] = {z, z, z, z};
        #pragma unroll
        for (int ks = 0; ks < 8; ++ks) {
          #pragma unroll
          for (int nt = 0; nt < 4; ++nt) {
            bf16x8 bk = ld16(hs2 + ((size_t)n * T_ + s0 + nt * 16 + l15) * H2_ + ks * 32 + quad * 8);
            sc[nt] = mfma_bf16(aq[ks], bk, sc[nt]);
          }
        }
        if (st == qt) {
          int qg = q0 + wave * 16 + quad * 4;
          #pragma unroll
          for (int nt = 0; nt < 4; ++nt) {
            int sg = s0 + nt * 16 + l15;
            #pragma unroll
            for (int r = 0; r < 4; ++r)
              if (sg > qg + r) sc[nt][r] = -1e30f;
          }
        }
        float alpha[4];
        #pragma unroll
        for (int r = 0; r < 4; ++r) {
          float tm = fmaxf(fmaxf(sc[0][r], sc[1][r]), fmaxf(sc[2][r], sc[3][r]));
          tm = fmaxf(tm, __shfl_xor(tm, 1, 16));
          tm = fmaxf(tm, __shfl_xor(tm, 2, 16));
          tm = fmaxf(tm, __shfl_xor(tm, 4, 16));
          tm = fmaxf(tm, __shfl_xor(tm, 8, 16));
          float mnew = fmaxf(m_run[r], tm);
          alpha[r] = __expf(m_run[r] - mnew);
          m_run[r] = mnew;
          float ts = 0.f;
          #pragma unroll
          for (int nt = 0; nt < 4; ++nt) {
            float p = __expf(sc[nt][r] - mnew);
            sc[nt][r] = p;
            ts += p;
          }
          ts += __shfl_xor(ts, 1, 16);
          ts += __shfl_xor(ts, 2, 16);
          ts += __shfl_xor(ts, 4, 16);
          ts += __shfl_xor(ts, 8, 16);
          l_run[r] = l_run[r] * alpha[r] + ts;
        }
        #pragma unroll
        for (int ct = 0; ct < 16; ++ct)
          #pragma unroll
          for (int r = 0; r < 4; ++r)
            o[ct][r] *= alpha[r];
        #pragma unroll
        for (int nt = 0; nt < 4; ++nt)
          #pragma unroll
          for (int r = 0; r < 4; ++r)
            pw[(quad * 4 + r) * 72 + nt * 16 + l15] = __float2bfloat16(sc[nt][r]);
        #pragma unroll
        for (int ks2 = 0; ks2 < 2; ++ks2) {
          bf16x8 ap = ld16(pw + l15 * 72 + ks2 * 32 + quad * 8);
          #pragma unroll
          for (int ct = 0; ct < 16; ++ct) {
            bf16x8 bv = ld16((bf16_t*)vtile + (ct * 16 + l15) * 72 + ks2 * 32 + quad * 8);
            o[ct] = mfma_bf16(ap, bv, o[ct]);
          }
        }
      }
      __syncthreads();
      float inv[4];
      #pragma unroll
      for (int r = 0; r < 4; ++r) inv[r] = 1.f / l_run[r];
      #pragma unroll
      for (int ct = 0; ct < 16; ++ct)
        #pragma unroll
        for (int r = 0; r < 4; ++r)
          ctxlds[(wave * 16 + quad * 4 + r) * 264 + ct * 16 + l15] =
              __float2bfloat16(o[ct][r] * inv[r]);
      __syncthreads();

      // fc1: K=512 (ctx|hs2) -> 128 ch, wave owns 32 channels
      f32x4 a1[4][2];
      #pragma unroll
      for (int mt = 0; mt < 4; ++mt) { a1[mt][0] = z; a1[mt][1] = z; }
      #pragma unroll
      for (int ks = 0; ks < 16; ++ks) {
        bf16x8 af[4];
        if (ks < 8) {
          #pragma unroll
          for (int mt = 0; mt < 4; ++mt)
            af[mt] = ld16(ctxlds + (mt * 16 + l15) * 264 + ks * 32 + quad * 8);
        } else {
          #pragma unroll
          for (int mt = 0; mt < 4; ++mt)
            af[mt] = ld16(hs2 + ((size_t)n * T_ + q0 + mt * 16 + l15) * H2_ + (ks - 8) * 32 + quad * 8);
        }
        #pragma unroll
        for (int nt = 0; nt < 2; ++nt) {
          bf16x8 bw = ld16(f1w + (size_t)(wave * 32 + nt * 16 + l15) * 512 + ks * 32 + quad * 8);
          #pragma unroll
          for (int mt = 0; mt < 4; ++mt)
            a1[mt][nt] = mfma_bf16(af[mt], bw, a1[mt][nt]);
        }
      }
      #pragma unroll
      for (int mt = 0; mt < 4; ++mt)
        #pragma unroll
        for (int nt = 0; nt < 2; ++nt)
          #pragma unroll
          for (int r = 0; r < 4; ++r) {
            int ch = wave * 32 + nt * 16 + l15;
            float v = a1[mt][nt][r] + fc1b[ch];
            act1[(mt * 16 + quad * 4 + r) * 136 + ch] = __float2bfloat16(fmaxf(v, 0.f));
          }
      __syncthreads();

      // fc2: K=128 -> 51 ch (padded 64)
      f32x4 a2[4] = {z, z, z, z};
      #pragma unroll
      for (int ks = 0; ks < 4; ++ks) {
        bf16x8 bw = ld16(f2w + (wave * 16 + l15) * 128 + ks * 32 + quad * 8);
        #pragma unroll
        for (int mt = 0; mt < 4; ++mt) {
          bf16x8 af = ld16(act1 + (mt * 16 + l15) * 136 + ks * 32 + quad * 8);
          a2[mt] = mfma_bf16(af, bw, a2[mt]);
        }
      }
      __syncthreads();
      #pragma unroll
      for (int mt = 0; mt < 4; ++mt)
        #pragma unroll
        for (int r = 0; r < 4; ++r) {
          int ch = wave * 16 + l15;
          int rw = mt * 16 + quad * 4 + r;
          float v = a2[mt][r] + (ch < 51 ? fc2b[ch] : 0.f);
          act2[rw * 68 + ch] = fmaxf(v, 0.f);
        }
      __syncthreads();
      if (tid < 64) {
        float s = fc3b[0];
        for (int c = 0; c < 51; ++c) s += act2[tid * 68 + c] * fc3w[c];
        dout[(size_t)n * T_ + q0 + tid] = s;
      }
      __syncthreads();   // LDS reuse + itemslot reuse
    }
    if (burn == 0.1234567f)   // never true; keeps burn alive
      ((float*)(ws + OFF_BURN))[tid] = burn;
  }
}

extern "C" void kernel_launch(void* const* d_in, const int* in_sizes, int n_in,
                              void* d_out, int out_size, void* d_ws, size_t ws_size,
                              hipStream_t stream) {
  (void)in_sizes; (void)n_in; (void)out_size; (void)ws_size;
  const float* x    = (const float*)d_in[0];
  const float* Wih1 = (const float*)d_in[1];
  const float* Whh1 = (const float*)d_in[2];
  const float* bih1 = (const float*)d_in[3];
  const float* bhh1 = (const float*)d_in[4];
  const float* Wih2 = (const float*)d_in[5];
  const float* Whh2 = (const float*)d_in[6];
  const float* bih2 = (const float*)d_in[7];
  const float* bhh2 = (const float*)d_in[8];
  const float* fc1w = (const float*)d_in[9];
  const float* fc1b = (const float*)d_in[10];
  const float* fc2w = (const float*)d_in[11];
  const float* fc2b = (const float*)d_in[12];
  const float* fc3w = (const float*)d_in[13];
  const float* fc3b = (const float*)d_in[14];
  char* ws  = (char*)d_ws;
  float* out = (float*)d_out;

  hipMemsetAsync(ws, 0, ZERO_BYTES, stream);   // flags + work queue
  setup_kernel<<<2048, 256, 0, stream>>>(x, Wih1, Whh1, bih1, bhh1,
                                         Wih2, Whh2, bih2, bhh2, fc1w, fc2w, ws);
  fused_kernel<<<256, 256, 0, stream>>>(ws, fc1b, fc2b, fc3w, fc3b, out);
}